// Round 3
// baseline (368.931 us; speedup 1.0000x reference)
//
#include <hip/hip_runtime.h>
#include <math.h>

// GRU cell, per-position weights. B=16,N=207,C=64,H=64 -> 3312 positions.
// v5: wave-per-position, ZERO barriers. v2(47%occ)/v3(75%)/v4(49%) all pinned
// at 115-121us = 2.8 TB/s effective (half the 10 B/cy/CU stream ceiling),
// warm-L3 == cold -> CU-side serialization. Suspects: per-block __syncthreads
// drains (s_waitcnt vmcnt(0) x4 per short block) + shallow load windows.
// v5: one wave owns one position; all reductions via __shfl_xor(16/32); the
// r-dependency handled by a 2-pass split (pass1: all Wx + Wh r-cols; pass2:
// Wh z+c cols vs h and r*h) -- every weight byte still read exactly once.
// No LDS, no s_barrier anywhere, fully-unrolled independent float4 streams.

#define GC 64    // input channels
#define GH 64    // hidden
#define J3 192   // 3*H
#define WPP (GC * J3)   // floats per weight matrix per position

__device__ __forceinline__ float sigm(float v) {
    return 1.f / (1.f + expf(-v));
}

__global__ __launch_bounds__(256, 4) void gru_cell_v5(
    const float* __restrict__ x,      // (P, 64)
    const float* __restrict__ state,  // (P, 64)
    const float* __restrict__ Wx,     // (P, 64, 192)
    const float* __restrict__ Wh,     // (P, 64, 192)
    const float* __restrict__ b,      // (P, 192)
    float* __restrict__ out)          // (P, 64)
{
    const int lane = threadIdx.x & 63;
    const int wid  = threadIdx.x >> 6;
    const int pos  = blockIdx.x * 4 + wid;      // 3312 % 4 == 0, no guard

    const int rr = lane >> 4;    // row phase 0..3
    const int jg = lane & 15;    // float4 column 0..15 within a 64-col block

    // Per-lane inputs (wave-local broadcast via shfl later).
    const float xv  = x[(size_t)pos * GC + lane];
    const float hv  = state[(size_t)pos * GH + lane];
    const float bv0 = b[(size_t)pos * J3 + lane];
    const float bv1 = b[(size_t)pos * J3 + 64 + lane];
    const float bv2 = b[(size_t)pos * J3 + 128 + lane];

    const float4* __restrict__ Wx4 = (const float4*)(Wx + (size_t)pos * WPP);
    const float4* __restrict__ Wh4 = (const float4*)(Wh + (size_t)pos * WPP);

    float4 accR = {0.f,0.f,0.f,0.f};
    float4 accZ = {0.f,0.f,0.f,0.f};
    float4 accC = {0.f,0.f,0.f,0.f};

    // ---- Pass 1: all of Wx (3 col-blocks) + Wh r-columns. 64 independent
    // float4 loads per lane in a straight unrolled line; rows 4k..4k+3 per
    // iter -> each instr covers 4 x 256B fully-consumed segments.
    #pragma unroll
    for (int k = 0; k < 16; ++k) {
        const int c = 4 * k + rr;
        const int base = c * 48 + jg;
        const float4 wx0 = Wx4[base];
        const float4 wx1 = Wx4[base + 16];
        const float4 wx2 = Wx4[base + 32];
        const float4 wh0 = Wh4[base];
        const float xs = __shfl(xv, c);
        const float hs = __shfl(hv, c);
        accR.x += xs * wx0.x + hs * wh0.x;
        accR.y += xs * wx0.y + hs * wh0.y;
        accR.z += xs * wx0.z + hs * wh0.z;
        accR.w += xs * wx0.w + hs * wh0.w;
        accZ.x += xs * wx1.x; accZ.y += xs * wx1.y;
        accZ.z += xs * wx1.z; accZ.w += xs * wx1.w;
        accC.x += xs * wx2.x; accC.y += xs * wx2.y;
        accC.z += xs * wx2.z; accC.w += xs * wx2.w;
    }

    // Reduce r-gate across the 4 row phases (in-wave, no barrier).
    accR.x += __shfl_xor(accR.x, 16); accR.x += __shfl_xor(accR.x, 32);
    accR.y += __shfl_xor(accR.y, 16); accR.y += __shfl_xor(accR.y, 32);
    accR.z += __shfl_xor(accR.z, 16); accR.z += __shfl_xor(accR.z, 32);
    accR.w += __shfl_xor(accR.w, 16); accR.w += __shfl_xor(accR.w, 32);

    // r for this lane's 4 columns (4jg..4jg+3): gather bias, sigmoid.
    float4 rv;
    rv.x = sigm(accR.x + __shfl(bv0, 4 * jg + 0));
    rv.y = sigm(accR.y + __shfl(bv0, 4 * jg + 1));
    rv.z = sigm(accR.z + __shfl(bv0, 4 * jg + 2));
    rv.w = sigm(accR.w + __shfl(bv0, 4 * jg + 3));

    // Redistribute: lane c needs r[c]. Col c lives in lane (c>>2), comp c&3.
    {
        const int sl = lane >> 2;
        const float c0 = __shfl(rv.x, sl);
        const float c1 = __shfl(rv.y, sl);
        const float c2 = __shfl(rv.z, sl);
        const float c3 = __shfl(rv.w, sl);
        const int q = lane & 3;
        const float rl = (q == 0) ? c0 : (q == 1) ? c1 : (q == 2) ? c2 : c3;
        rv.x = rl * hv;   // reuse rv.x as rh[lane]
    }
    const float rhv = rv.x;

    // ---- Pass 2: Wh z-columns (vs h) and candidate columns (vs r*h). ----
    #pragma unroll
    for (int k = 0; k < 16; ++k) {
        const int c = 4 * k + rr;
        const int base = c * 48 + jg;
        const float4 wh1 = Wh4[base + 16];
        const float4 wh2 = Wh4[base + 32];
        const float hs = __shfl(hv, c);
        const float rs = __shfl(rhv, c);
        accZ.x += hs * wh1.x + 0.f;  accZ.y += hs * wh1.y;
        accZ.z += hs * wh1.z;        accZ.w += hs * wh1.w;
        accC.x += rs * wh2.x;        accC.y += rs * wh2.y;
        accC.z += rs * wh2.z;        accC.w += rs * wh2.w;
    }

    // Reduce z and candidate across row phases.
    accZ.x += __shfl_xor(accZ.x, 16); accZ.x += __shfl_xor(accZ.x, 32);
    accZ.y += __shfl_xor(accZ.y, 16); accZ.y += __shfl_xor(accZ.y, 32);
    accZ.z += __shfl_xor(accZ.z, 16); accZ.z += __shfl_xor(accZ.z, 32);
    accZ.w += __shfl_xor(accZ.w, 16); accZ.w += __shfl_xor(accZ.w, 32);
    accC.x += __shfl_xor(accC.x, 16); accC.x += __shfl_xor(accC.x, 32);
    accC.y += __shfl_xor(accC.y, 16); accC.y += __shfl_xor(accC.y, 32);
    accC.z += __shfl_xor(accC.z, 16); accC.z += __shfl_xor(accC.z, 32);
    accC.w += __shfl_xor(accC.w, 16); accC.w += __shfl_xor(accC.w, 32);

    // Finalize this lane's 4 columns.
    float4 zv, hcv, ov;
    zv.x  = sigm(accZ.x + __shfl(bv1, 4 * jg + 0));
    zv.y  = sigm(accZ.y + __shfl(bv1, 4 * jg + 1));
    zv.z  = sigm(accZ.z + __shfl(bv1, 4 * jg + 2));
    zv.w  = sigm(accZ.w + __shfl(bv1, 4 * jg + 3));
    hcv.x = tanhf(accC.x + __shfl(bv2, 4 * jg + 0));
    hcv.y = tanhf(accC.y + __shfl(bv2, 4 * jg + 1));
    hcv.z = tanhf(accC.z + __shfl(bv2, 4 * jg + 2));
    hcv.w = tanhf(accC.w + __shfl(bv2, 4 * jg + 3));
    const float h0 = __shfl(hv, 4 * jg + 0);
    const float h1 = __shfl(hv, 4 * jg + 1);
    const float h2 = __shfl(hv, 4 * jg + 2);
    const float h3 = __shfl(hv, 4 * jg + 3);
    ov.x = (1.f - zv.x) * h0 + zv.x * hcv.x;
    ov.y = (1.f - zv.y) * h1 + zv.y * hcv.y;
    ov.z = (1.f - zv.z) * h2 + zv.z * hcv.z;
    ov.w = (1.f - zv.w) * h3 + zv.w * hcv.w;

    // Lanes 0..15 (jg==lane) store the 64 outputs as 16 float4s.
    if (lane < 16) {
        ((float4*)(out + (size_t)pos * GH))[jg] = ov;
    }
}

extern "C" void kernel_launch(void* const* d_in, const int* in_sizes, int n_in,
                              void* d_out, int out_size, void* d_ws, size_t ws_size,
                              hipStream_t stream) {
    const float* x     = (const float*)d_in[0];
    const float* state = (const float*)d_in[1];
    const float* Wx    = (const float*)d_in[2];
    const float* Wh    = (const float*)d_in[3];
    const float* b     = (const float*)d_in[4];
    float* out = (float*)d_out;

    const int npos = in_sizes[0] / GC;   // B*N = 3312
    const int nblk = npos / 4;           // 4 waves (positions) per block

    gru_cell_v5<<<nblk, 256, 0, stream>>>(x, state, Wx, Wh, b, out);
}

// Round 4
// 316.825 us; speedup vs baseline: 1.1645x; 1.1645x over previous
//
#include <hip/hip_runtime.h>
#include <math.h>

// GRU cell, per-position weights. B=16,N=207,C=64,H=64 -> 3312 positions.
// v6 = v3 + NON-TEMPORAL weight loads. Evidence: v2/v3/v4 (three structures,
// 47-75% occupancy) all pin at 2.75 TB/s total read delivery (330MB/119us);
// CU-side limits are all >10x higher -> shared-path bound. FETCH=161MB of a
// 330MB stream shows ~half hits a thrashing 256MB IF$ (working set 306MB,
// zero intra-dispatch reuse): every miss pays an L3 fill/evict on a set that
// can never stay resident. nt bit = evict-first/no-retention policy for the
// weight stream; x/state/b (tiny, reused) stay normally cached.
// v5 post-mortem: WRITE_SIZE 0.8->83MB = scratch spills from full-unroll load
// hoisting, not a valid test of the zero-barrier theory. Reverted to v3 base.

#define GC 64    // input channels
#define GH 64    // hidden
#define J3 192   // 3*H
#define WPP (GC * J3)   // floats per weight matrix per position

typedef float f4 __attribute__((ext_vector_type(4)));

__global__ __launch_bounds__(256, 8) void gru_cell_v6(
    const float* __restrict__ x,      // (P, 64)
    const float* __restrict__ state,  // (P, 64)
    const float* __restrict__ Wx,     // (P, 64, 192)
    const float* __restrict__ Wh,     // (P, 64, 192)
    const float* __restrict__ b,      // (P, 192)
    float* __restrict__ out)          // (P, 64)
{
    const int pos = blockIdx.x;
    const int t = threadIdx.x;        // 0..255

    __shared__ float x_s[GC];
    __shared__ float mult_s[2 * GH];  // [0,64): h ; [64,128): r*h
    __shared__ float part[1024];      // phase1: [16][64] ; phase2: [8][128]
    __shared__ float z_s[GH];

    if (t < GC)           x_s[t]          = x[(size_t)pos * GC + t];
    else if (t < GC + GH) mult_s[t - GC]  = state[(size_t)pos * GH + (t - GC)];
    __syncthreads();

    const f4* __restrict__ Wx4 = (const f4*)(Wx + (size_t)pos * WPP);
    const f4* __restrict__ Wh4 = (const f4*)(Wh + (size_t)pos * WPP);

    // ---- Phase 1: r-gate columns 0..63 of both matrices ----
    // thread -> (f4col jg 0..15, row-phase rp 0..15); rows c = rp + 16k.
    {
        const int jg = t & 15;
        const int rp = t >> 4;
        f4 acc = {0.f, 0.f, 0.f, 0.f};
        #pragma unroll
        for (int k = 0; k < 4; ++k) {
            const int c = rp + 16 * k;
            const f4 wx4 = __builtin_nontemporal_load(Wx4 + c * 48 + jg);
            const f4 wh4 = __builtin_nontemporal_load(Wh4 + c * 48 + jg);
            const float xs = x_s[c];
            const float hs = mult_s[c];
            acc.x += xs * wx4.x + hs * wh4.x;
            acc.y += xs * wx4.y + hs * wh4.y;
            acc.z += xs * wx4.z + hs * wh4.z;
            acc.w += xs * wx4.w + hs * wh4.w;
        }
        *((f4*)&part[rp * 64 + 4 * jg]) = acc;  // contiguous f4, conflict-free
    }
    __syncthreads();

    // Reduce 16 row-phases; compute r and rh = r*h.
    if (t < GH) {
        float v = b[(size_t)pos * J3 + t];
        #pragma unroll
        for (int rp = 0; rp < 16; ++rp) v += part[rp * 64 + t];
        const float r = 1.f / (1.f + expf(-v));
        mult_s[GH + t] = r * mult_s[t];
    }
    __syncthreads();

    // ---- Phase 2: z columns (64..127, mult = h) and candidate (128..191,
    // mult = rh). Multiplier picked by computed LDS address: zero divergence.
    float vc = 0.f;
    {
        const int jg = t & 31;
        const int rp = t >> 5;
        const int msel = (jg & 16) << 2;   // 0 -> h, 64 -> rh
        f4 acc = {0.f, 0.f, 0.f, 0.f};
        #pragma unroll 4
        for (int k = 0; k < 8; ++k) {
            const int c = rp + 8 * k;
            const f4 wx4 = __builtin_nontemporal_load(Wx4 + c * 48 + 16 + jg);
            const f4 wh4 = __builtin_nontemporal_load(Wh4 + c * 48 + 16 + jg);
            const float xs = x_s[c];
            const float ms = mult_s[msel + c];
            acc.x += xs * wx4.x + ms * wh4.x;
            acc.y += xs * wx4.y + ms * wh4.y;
            acc.z += xs * wx4.z + ms * wh4.z;
            acc.w += xs * wx4.w + ms * wh4.w;
        }
        *((f4*)&part[rp * 128 + 4 * jg]) = acc;
    }
    __syncthreads();

    // Reduce 8 row-phases. t<64 owns z column t; t in [64,128) owns candidate.
    if (t < 2 * GH) {
        float v = b[(size_t)pos * J3 + GH + t];
        #pragma unroll
        for (int rp = 0; rp < 8; ++rp) v += part[rp * 128 + t];
        if (t < GH) z_s[t] = 1.f / (1.f + expf(-v));
        else        vc = v;
    }
    __syncthreads();

    if (t >= GH && t < 2 * GH) {
        const int j = t - GH;
        const float hc = tanhf(vc);
        const float z = z_s[j];
        out[(size_t)pos * GH + j] = (1.f - z) * mult_s[j] + z * hc;
    }
}

extern "C" void kernel_launch(void* const* d_in, const int* in_sizes, int n_in,
                              void* d_out, int out_size, void* d_ws, size_t ws_size,
                              hipStream_t stream) {
    const float* x     = (const float*)d_in[0];
    const float* state = (const float*)d_in[1];
    const float* Wx    = (const float*)d_in[2];
    const float* Wh    = (const float*)d_in[3];
    const float* b     = (const float*)d_in[4];
    float* out = (float*)d_out;

    const int npos = in_sizes[0] / GC;   // B*N = 3312

    gru_cell_v6<<<npos, 256, 0, stream>>>(x, state, Wx, Wh, b, out);
}

// Round 5
// 308.171 us; speedup vs baseline: 1.1972x; 1.0281x over previous
//
#include <hip/hip_runtime.h>
#include <math.h>

// GRU cell, per-position weights. B=16,N=207,C=64,H=64 -> 3312 positions.
// v7 = v6 (non-temporal weight stream; confirmed win: kernel dropped below
// the 95us harness fills, bench 332->317) + structural cleanup:
//  - barrier count 4 -> 3: x/h staged wave-redundantly + __shfl broadcast
//    (no initial __syncthreads).
//  - phase rebalance: z and x.Wxc don't depend on r, only the candidate's
//    h-term does. Phase 1 streams ALL of Wx + Wh's r,z cols (5/6 of bytes,
//    20 nt float4 loads/thread, one vmcnt drain); phase 2 streams only
//    Wh's candidate cols (1/6) against r*h. Candidate x-partials persist in
//    registers across the serial r-section (same (jg,rp) mapping both phases).
// Every weight byte still read exactly once, all weight loads nt.

#define GC 64    // input channels
#define GH 64    // hidden
#define J3 192   // 3*H
#define WPP (GC * J3)   // floats per weight matrix per position

typedef float f4 __attribute__((ext_vector_type(4)));

__device__ __forceinline__ float sigm(float v) {
    return 1.f / (1.f + expf(-v));
}

__global__ __launch_bounds__(256, 8) void gru_cell_v7(
    const float* __restrict__ x,      // (P, 64)
    const float* __restrict__ state,  // (P, 64)
    const float* __restrict__ Wx,     // (P, 64, 192)
    const float* __restrict__ Wh,     // (P, 64, 192)
    const float* __restrict__ b,      // (P, 192)
    float* __restrict__ out)          // (P, 64)
{
    const int pos  = blockIdx.x;
    const int t    = threadIdx.x;     // 0..255
    const int lane = t & 63;

    __shared__ float rh_s[GH];        // r*h, published by wave 0
    __shared__ float z_s[GH];
    __shared__ float part[16 * 128];  // 8 KB partial-sum scratch (reused)

    // Wave-redundant input broadcast copies: no barrier needed before phase 1.
    const float xv = x[(size_t)pos * GC + lane];
    const float hv = state[(size_t)pos * GH + lane];
    float bA = 0.f, bC = 0.f;
    if (t < 128) bA = b[(size_t)pos * J3 + t];          // br (t<64) / bz
    if (t < 64)  bC = b[(size_t)pos * J3 + 128 + t];    // bc

    const f4* __restrict__ Wx4 = (const f4*)(Wx + (size_t)pos * WPP);
    const f4* __restrict__ Wh4 = (const f4*)(Wh + (size_t)pos * WPP);

    const int jg = t & 15;       // float4 column 0..15 within a 64-col block
    const int rp = t >> 4;       // row phase 0..15; rows c = rp + 16k

    f4 accR = {0.f,0.f,0.f,0.f};
    f4 accZ = {0.f,0.f,0.f,0.f};
    f4 accC = {0.f,0.f,0.f,0.f};

    // ---- Phase 1: all Wx cols + Wh r,z cols. 20 nt float4 loads/thread;
    // each instr covers 4 x 256B fully-consumed segments.
    #pragma unroll
    for (int k = 0; k < 4; ++k) {
        const int c = rp + 16 * k;
        const int base = c * 48 + jg;
        const f4 wxr = __builtin_nontemporal_load(Wx4 + base);
        const f4 wxz = __builtin_nontemporal_load(Wx4 + base + 16);
        const f4 wxc = __builtin_nontemporal_load(Wx4 + base + 32);
        const f4 whr = __builtin_nontemporal_load(Wh4 + base);
        const f4 whz = __builtin_nontemporal_load(Wh4 + base + 16);
        const float xs = __shfl(xv, c);
        const float hs = __shfl(hv, c);
        accR.x += xs * wxr.x + hs * whr.x;
        accR.y += xs * wxr.y + hs * whr.y;
        accR.z += xs * wxr.z + hs * whr.z;
        accR.w += xs * wxr.w + hs * whr.w;
        accZ.x += xs * wxz.x + hs * whz.x;
        accZ.y += xs * wxz.y + hs * whz.y;
        accZ.z += xs * wxz.z + hs * whz.z;
        accZ.w += xs * wxz.w + hs * whz.w;
        accC.x += xs * wxc.x;
        accC.y += xs * wxc.y;
        accC.z += xs * wxc.z;
        accC.w += xs * wxc.w;
    }
    *((f4*)&part[rp * 128 + 4 * jg])      = accR;
    *((f4*)&part[rp * 128 + 64 + 4 * jg]) = accZ;
    __syncthreads();

    // Reduce r,z across 16 row phases; publish rh and z. (accC stays in regs.)
    if (t < 128) {
        float v = bA;
        #pragma unroll
        for (int p = 0; p < 16; ++p) v += part[p * 128 + t];
        if (t < 64) rh_s[t]      = sigm(v) * hv;   // wave 0: hv == h[t]
        else        z_s[t - 64]  = sigm(v);
    }
    __syncthreads();

    // ---- Phase 2: Wh candidate cols (1/6 of bytes) vs r*h. ----
    #pragma unroll
    for (int k = 0; k < 4; ++k) {
        const int c = rp + 16 * k;
        const f4 whc = __builtin_nontemporal_load(Wh4 + c * 48 + 32 + jg);
        const float rs = rh_s[c];
        accC.x += rs * whc.x;
        accC.y += rs * whc.y;
        accC.z += rs * whc.z;
        accC.w += rs * whc.w;
    }
    *((f4*)&part[rp * 64 + 4 * jg]) = accC;
    __syncthreads();

    // Final reduce + gate combine; wave 0 stores the 64 outputs (256B line).
    if (t < 64) {
        float v = bC;
        #pragma unroll
        for (int p = 0; p < 16; ++p) v += part[p * 64 + t];
        const float hc = tanhf(v);
        const float z  = z_s[t];
        out[(size_t)pos * GH + t] = (1.f - z) * hv + z * hc;
    }
}

extern "C" void kernel_launch(void* const* d_in, const int* in_sizes, int n_in,
                              void* d_out, int out_size, void* d_ws, size_t ws_size,
                              hipStream_t stream) {
    const float* x     = (const float*)d_in[0];
    const float* state = (const float*)d_in[1];
    const float* Wx    = (const float*)d_in[2];
    const float* Wh    = (const float*)d_in[3];
    const float* b     = (const float*)d_in[4];
    float* out = (float*)d_out;

    const int npos = in_sizes[0] / GC;   // B*N = 3312

    gru_cell_v7<<<npos, 256, 0, stream>>>(x, state, Wx, Wh, b, out);
}

// Round 6
// 308.063 us; speedup vs baseline: 1.1976x; 1.0004x over previous
//
#include <hip/hip_runtime.h>
#include <math.h>

// GRU cell, per-position weights. B=16,N=207,C=64,H=64 -> 3312 positions.
// v8 = v7 + soft barriers + single-burst weight stream.
// History: v2-v4 ~115-120us (L3-blend path bound); v6 nt-loads -> ~99us;
// v7 phase-rebalance -> ~90us. Remaining gap vs ~50us pure-stream floor:
// each __syncthreads = s_waitcnt vmcnt(0) drain; 3 per block, convoying
// co-resident blocks -> CU-wide vmem-idle windows (the documented barrier
// drain stall). All cross-wave comms here are LDS-only, so:
//  - soft_barrier(): s_waitcnt lgkmcnt(0) + raw s_barrier (loads stay in
//    flight across barriers; sched_barrier fences per guide rule #18).
//  - phase-2 candidate weights (whc[4], 16 VGPR) load in the phase-1 burst:
//    the whole 96KB/position stream issues as ONE 24-load burst; the serial
//    r/z section runs under outstanding loads, not after a drain.
// __launch_bounds__(256,4): register room, no spills (v5 lesson: watch
// WRITE_SIZE; 828KB = clean, MBs = spill).

#define GC 64    // input channels
#define GH 64    // hidden
#define J3 192   // 3*H
#define WPP (GC * J3)   // floats per weight matrix per position

typedef float f4 __attribute__((ext_vector_type(4)));

__device__ __forceinline__ float sigm(float v) {
    return 1.f / (1.f + expf(-v));
}

// LDS-only barrier: completes this wave's ds ops, syncs, does NOT drain vmem.
__device__ __forceinline__ void soft_barrier() {
    __builtin_amdgcn_sched_barrier(0);
    asm volatile("s_waitcnt lgkmcnt(0)" ::: "memory");
    __builtin_amdgcn_s_barrier();
    __builtin_amdgcn_sched_barrier(0);
}

__global__ __launch_bounds__(256, 4) void gru_cell_v8(
    const float* __restrict__ x,      // (P, 64)
    const float* __restrict__ state,  // (P, 64)
    const float* __restrict__ Wx,     // (P, 64, 192)
    const float* __restrict__ Wh,     // (P, 64, 192)
    const float* __restrict__ b,      // (P, 192)
    float* __restrict__ out)          // (P, 64)
{
    const int pos  = blockIdx.x;
    const int t    = threadIdx.x;     // 0..255
    const int lane = t & 63;

    __shared__ float rh_s[GH];        // r*h, published by wave 0
    __shared__ float z_s[GH];
    __shared__ float part[16 * 128];  // 8 KB partial-sum scratch (reused)

    // Wave-redundant input broadcasts: no barrier before the stream.
    const float xv = x[(size_t)pos * GC + lane];
    const float hv = state[(size_t)pos * GH + lane];
    float bA = 0.f, bC = 0.f;
    if (t < 128) bA = b[(size_t)pos * J3 + t];          // br (t<64) / bz
    if (t < 64)  bC = b[(size_t)pos * J3 + 128 + t];    // bc

    const f4* __restrict__ Wx4 = (const f4*)(Wx + (size_t)pos * WPP);
    const f4* __restrict__ Wh4 = (const f4*)(Wh + (size_t)pos * WPP);

    const int jg = t & 15;       // float4 column 0..15 within a 64-col block
    const int rp = t >> 4;       // row phase 0..15; rows c = rp + 16k

    f4 accR = {0.f,0.f,0.f,0.f};
    f4 accZ = {0.f,0.f,0.f,0.f};
    f4 accC = {0.f,0.f,0.f,0.f};
    f4 whc[4];                   // candidate Wh cols: loaded now, used phase 2

    // ---- Single burst: ALL 24 nt float4 loads for this position. ----
    #pragma unroll
    for (int k = 0; k < 4; ++k) {
        const int c = rp + 16 * k;
        const int base = c * 48 + jg;
        const f4 wxr = __builtin_nontemporal_load(Wx4 + base);
        const f4 wxz = __builtin_nontemporal_load(Wx4 + base + 16);
        const f4 wxc = __builtin_nontemporal_load(Wx4 + base + 32);
        const f4 whr = __builtin_nontemporal_load(Wh4 + base);
        const f4 whz = __builtin_nontemporal_load(Wh4 + base + 16);
        whc[k]       = __builtin_nontemporal_load(Wh4 + base + 32);
        const float xs = __shfl(xv, c);
        const float hs = __shfl(hv, c);
        accR.x += xs * wxr.x + hs * whr.x;
        accR.y += xs * wxr.y + hs * whr.y;
        accR.z += xs * wxr.z + hs * whr.z;
        accR.w += xs * wxr.w + hs * whr.w;
        accZ.x += xs * wxz.x + hs * whz.x;
        accZ.y += xs * wxz.y + hs * whz.y;
        accZ.z += xs * wxz.z + hs * whz.z;
        accZ.w += xs * wxz.w + hs * whz.w;
        accC.x += xs * wxc.x;
        accC.y += xs * wxc.y;
        accC.z += xs * wxc.z;
        accC.w += xs * wxc.w;
    }
    *((f4*)&part[rp * 128 + 4 * jg])      = accR;
    *((f4*)&part[rp * 128 + 64 + 4 * jg]) = accZ;
    soft_barrier();              // whc loads stay in flight through here

    // Reduce r,z across 16 row phases; publish rh and z.
    if (t < 128) {
        float v = bA;
        #pragma unroll
        for (int p = 0; p < 16; ++p) v += part[p * 128 + t];
        if (t < 64) rh_s[t]      = sigm(v) * hv;   // wave 0: hv == h[t]
        else        z_s[t - 64]  = sigm(v);
    }
    soft_barrier();

    // ---- Phase 2: candidate FMAs from registers (whc landed long ago). ----
    #pragma unroll
    for (int k = 0; k < 4; ++k) {
        const int c = rp + 16 * k;
        const float rs = rh_s[c];
        accC.x += rs * whc[k].x;
        accC.y += rs * whc[k].y;
        accC.z += rs * whc[k].z;
        accC.w += rs * whc[k].w;
    }
    *((f4*)&part[rp * 64 + 4 * jg]) = accC;
    soft_barrier();

    // Final reduce + gate combine; wave 0 stores the 64 outputs (256B line).
    if (t < 64) {
        float v = bC;
        #pragma unroll
        for (int p = 0; p < 16; ++p) v += part[p * 64 + t];
        const float hc = tanhf(v);
        const float z  = z_s[t];
        out[(size_t)pos * GH + t] = (1.f - z) * hv + z * hc;
    }
}

extern "C" void kernel_launch(void* const* d_in, const int* in_sizes, int n_in,
                              void* d_out, int out_size, void* d_ws, size_t ws_size,
                              hipStream_t stream) {
    const float* x     = (const float*)d_in[0];
    const float* state = (const float*)d_in[1];
    const float* Wx    = (const float*)d_in[2];
    const float* Wh    = (const float*)d_in[3];
    const float* b     = (const float*)d_in[4];
    float* out = (float*)d_out;

    const int npos = in_sizes[0] / GC;   // B*N = 3312

    gru_cell_v8<<<npos, 256, 0, stream>>>(x, state, Wx, Wh, b, out);
}